// Round 1
// baseline (1121.326 us; speedup 1.0000x reference)
//
#include <hip/hip_runtime.h>

#define NN  25000
#define EE  500000
#define BB  4
#define DD  32
#define R2C 474
#define LL  4
#define BD  128      // B*D
#define THD 416      // 13*D
#define EPSF 1e-6f
#define NPB 8

// ---------------- CSR build ----------------
__global__ __launch_bounds__(256) void hist_kernel(const int* __restrict__ node_out,
                                                   const float* __restrict__ ew,
                                                   int* __restrict__ cnt,
                                                   float* __restrict__ wdeg) {
  int e = blockIdx.x * 256 + threadIdx.x;
  if (e < EE) {
    int d = node_out[e];
    atomicAdd(&cnt[d], 1);
    atomicAdd(&wdeg[d], ew[e]);
  }
}

__global__ __launch_bounds__(1024) void scan_kernel(const int* __restrict__ cnt,
                                                    int* __restrict__ rowp,
                                                    const float* __restrict__ wdeg,
                                                    float* __restrict__ stats,
                                                    float* __restrict__ cntf) {
  __shared__ int   part[1024];
  __shared__ float fpart[1024];
  int t = threadIdx.x;
  const int per = (NN + 1023) / 1024;   // 25
  int beg = t * per, end = min(beg + per, NN);
  int s = 0; float ls = 0.f;
  for (int i = beg; i < end; ++i) { s += cnt[i]; ls += logf(wdeg[i] + 1.0f); }
  part[t] = s; fpart[t] = ls;
  __syncthreads();
  for (int off = 1; off < 1024; off <<= 1) {
    int   v  = (t >= off) ? part[t - off]  : 0;
    float fv = (t >= off) ? fpart[t - off] : 0.f;
    __syncthreads();
    part[t] += v; fpart[t] += fv;
    __syncthreads();
  }
  int run = part[t] - s;   // exclusive prefix of this thread's chunk
  for (int i = beg; i < end; ++i) {
    rowp[i] = run; run += cnt[i];
    cntf[i] = (float)(cnt[i] + 1);      // indeg + self entry
  }
  if (t == 1023) { rowp[NN] = part[1023]; stats[0] = fpart[1023]; }
}

__global__ __launch_bounds__(256) void scales_kernel(const float* __restrict__ wdeg,
                                                     const float* __restrict__ stats,
                                                     float* __restrict__ scales) {
  int n = blockIdx.x * 256 + threadIdx.x;
  if (n >= NN) return;
  float mean = stats[0] / (float)NN;
  float sc = logf(wdeg[n] + 1.0f) / mean;
  scales[n * 3 + 0] = 1.0f;
  scales[n * 3 + 1] = sc;
  scales[n * 3 + 2] = 1.0f / fmaxf(sc, 0.01f);
}

__global__ __launch_bounds__(256) void scatter_kernel(const int* __restrict__ node_in,
                                                      const int* __restrict__ node_out,
                                                      const int* __restrict__ relation,
                                                      const float* __restrict__ ew,
                                                      const int* __restrict__ rowp,
                                                      int* __restrict__ fill,
                                                      int* __restrict__ snin,
                                                      int* __restrict__ srel,
                                                      float* __restrict__ sw) {
  int e = blockIdx.x * 256 + threadIdx.x;
  if (e >= EE) return;
  int dn = node_out[e];
  int pos = rowp[dn] + atomicAdd(&fill[dn], 1);
  snin[pos] = node_in[e];
  srel[pos] = relation[e];
  sw[pos]   = ew[e];
}

// query gather + boundary placement (h0 pre-zeroed by memset)
__global__ __launch_bounds__(128) void init_kernel(const int* __restrict__ h_index,
                                                   const int* __restrict__ r_index,
                                                   const float* __restrict__ qemb,
                                                   float* __restrict__ query,
                                                   float* __restrict__ h0) {
  int t = threadIdx.x; int b = t >> 5, d = t & 31;
  float qv = qemb[r_index[b] * DD + d];
  query[t] = qv;
  h0[h_index[b] * BD + t] = qv;
}

// rel_in[r][b][d] = query[b] . rel_W[l][:, r*D+d] + rel_b[l][r*D+d]
__global__ __launch_bounds__(256) void relin_kernel(const float* __restrict__ query,
                                                    const float* __restrict__ relW,
                                                    const float* __restrict__ relB,
                                                    float* __restrict__ relIn) {
  int o = blockIdx.x * 256 + threadIdx.x;
  if (o >= R2C * BD) return;
  int r = o >> 7; int b = (o >> 5) & 3; int d = o & 31;
  int col = r * DD + d;
  float acc = relB[col];
  #pragma unroll
  for (int k = 0; k < DD; ++k)
    acc = fmaf(query[b * DD + k], relW[(size_t)k * (R2C * DD) + col], acc);
  relIn[o] = acc;   // o == r*128 + b*32 + d
}

// main fused layer: gather-reduce PNA stats + scales + 416->32 linear + relu
__global__ __launch_bounds__(128) void layer_kernel(const float* __restrict__ hin,
                                                    float* __restrict__ hout,
                                                    const float* __restrict__ relIn,
                                                    const int* __restrict__ snin,
                                                    const int* __restrict__ srel,
                                                    const float* __restrict__ sw,
                                                    const int* __restrict__ rowp,
                                                    const float* __restrict__ cntf,
                                                    const float* __restrict__ scales,
                                                    const float* __restrict__ W,
                                                    const float* __restrict__ bias,
                                                    const int* __restrict__ h_index,
                                                    const float* __restrict__ query) {
  __shared__ float feat13[BB][THD + 1];   // +1 pad breaks bank aliasing
  const int t = threadIdx.x;
  const int b = t >> 5, d = t & 31;
  const float qv = query[t];
  const int   hb = h_index[b];
  const float bj = bias[d];
  int n0 = blockIdx.x * NPB;
  int n1 = min(n0 + NPB, NN);
  for (int n = n0; n < n1; ++n) {
    int beg = rowp[n], end = rowp[n + 1];
    // boundary self-message (weight 1) initializes all four accumulators
    float msgb = (n == hb) ? qv : 0.f;
    float s = msgb, q = msgb * msgb, mx = msgb, mn = msgb;
    float hs = hin[(size_t)n * BD + t];
    int p = beg;
    for (; p + 1 < end; p += 2) {
      int nin0 = snin[p];     int rel0 = srel[p];     float w0 = sw[p];
      int nin1 = snin[p + 1]; int rel1 = srel[p + 1]; float w1 = sw[p + 1];
      float hv0 = hin[(size_t)nin0 * BD + t];
      float rv0 = relIn[(size_t)rel0 * BD + t];
      float hv1 = hin[(size_t)nin1 * BD + t];
      float rv1 = relIn[(size_t)rel1 * BD + t];
      float m0 = rv0 * hv0, mw0 = m0 * w0;
      float m1 = rv1 * hv1, mw1 = m1 * w1;
      s += mw0; q = fmaf(m0, mw0, q); mx = fmaxf(mx, mw0); mn = fminf(mn, mw0);
      s += mw1; q = fmaf(m1, mw1, q); mx = fmaxf(mx, mw1); mn = fminf(mn, mw1);
    }
    for (; p < end; ++p) {
      int nin = snin[p]; int rel = srel[p]; float w = sw[p];
      float hv = hin[(size_t)nin * BD + t];
      float rv = relIn[(size_t)rel * BD + t];
      float m = rv * hv, mw = m * w;
      s += mw; q = fmaf(m, mw, q); mx = fmaxf(mx, mw); mn = fminf(mn, mw);
    }
    float invc = 1.0f / cntf[n];
    float mean = s * invc;
    float sq   = q * invc;
    float sd   = sqrtf(fmaxf(sq - mean * mean, EPSF));
    float sc1 = scales[n * 3 + 1], sc2 = scales[n * 3 + 2];
    float fv[4] = {mean, mx, mn, sd};
    float* fb = feat13[b];
    fb[d] = hs;
    #pragma unroll
    for (int si = 0; si < 4; ++si) {
      int base = DD + (d * 4 + si) * 3;
      float v = fv[si];
      fb[base] = v; fb[base + 1] = v * sc1; fb[base + 2] = v * sc2;
    }
    __syncthreads();
    float acc = bj;
    const float* fbb = feat13[b];
    #pragma unroll 8
    for (int i = 0; i < THD; ++i)
      acc = fmaf(fbb[i], W[(size_t)i * DD + d], acc);
    hout[(size_t)n * BD + t] = fmaxf(acc, 0.f);
    __syncthreads();
  }
}

// final MLP: [hidden, query] (64) -> relu(64) -> 1, write out[b*N + n]
__global__ __launch_bounds__(128) void mlp_kernel(const float* __restrict__ hin,
                                                  const float* __restrict__ query,
                                                  const float* __restrict__ W1,
                                                  const float* __restrict__ b1,
                                                  const float* __restrict__ W2,
                                                  const float* __restrict__ b2,
                                                  float* __restrict__ out) {
  __shared__ float f2[BB][2 * DD];
  const int t = threadIdx.x;
  const int b = t >> 5, d = t & 31;
  const float qv = query[t];
  const float w2a = W2[d], w2b = W2[DD + d];
  const float b1a = b1[d], b1b = b1[DD + d];
  const float b2v = b2[0];
  int n0 = blockIdx.x * NPB, n1 = min(n0 + NPB, NN);
  for (int n = n0; n < n1; ++n) {
    f2[b][d]      = hin[(size_t)n * BD + t];
    f2[b][DD + d] = qv;
    __syncthreads();
    float a0 = b1a, a1 = b1b;
    #pragma unroll
    for (int i = 0; i < 2 * DD; ++i) {
      float v = f2[b][i];
      a0 = fmaf(v, W1[i * 2 * DD + d], a0);
      a1 = fmaf(v, W1[i * 2 * DD + DD + d], a1);
    }
    a0 = fmaxf(a0, 0.f); a1 = fmaxf(a1, 0.f);
    float part = a0 * w2a + a1 * w2b;
    #pragma unroll
    for (int off = 16; off > 0; off >>= 1) part += __shfl_down(part, off, 32);
    if (d == 0) out[b * NN + n] = part + b2v;
    __syncthreads();
  }
}

extern "C" void kernel_launch(void* const* d_in, const int* in_sizes, int n_in,
                              void* d_out, int out_size, void* d_ws, size_t ws_size,
                              hipStream_t stream) {
  const int*   node_in  = (const int*)d_in[0];
  const int*   node_out = (const int*)d_in[1];
  const int*   relation = (const int*)d_in[2];
  const float* ew       = (const float*)d_in[3];
  const int*   h_index  = (const int*)d_in[4];
  const int*   r_index  = (const int*)d_in[5];
  const float* qemb     = (const float*)d_in[6];
  const float* relW     = (const float*)d_in[7];
  const float* relB     = (const float*)d_in[8];
  const float* linW     = (const float*)d_in[9];
  const float* linB     = (const float*)d_in[10];
  const float* W1       = (const float*)d_in[11];
  const float* b1       = (const float*)d_in[12];
  const float* W2       = (const float*)d_in[13];
  const float* b2       = (const float*)d_in[14];
  float* out = (float*)d_out;

  char* ws = (char*)d_ws;
  size_t off = 0;
  auto alloc = [&](size_t bytes) -> char* {
    char* p = ws + off;
    off += (bytes + 255) & ~(size_t)255;
    return p;
  };
  float* h0     = (float*)alloc((size_t)NN * BD * 4);
  float* h1     = (float*)alloc((size_t)NN * BD * 4);
  float* relIn  = (float*)alloc((size_t)R2C * BD * 4);
  int*   snin   = (int*)  alloc((size_t)EE * 4);
  int*   srel   = (int*)  alloc((size_t)EE * 4);
  float* sw     = (float*)alloc((size_t)EE * 4);
  int*   rowp   = (int*)  alloc((size_t)(NN + 1) * 4);
  int*   cnti   = (int*)  alloc((size_t)NN * 4);
  int*   fill   = (int*)  alloc((size_t)NN * 4);
  float* wdeg   = (float*)alloc((size_t)NN * 4);
  float* cntf   = (float*)alloc((size_t)NN * 4);
  float* scales = (float*)alloc((size_t)NN * 3 * 4);
  float* query  = (float*)alloc((size_t)BD * 4);
  float* stats  = (float*)alloc(256);

  hipMemsetAsync(cnti, 0, (size_t)NN * 4, stream);
  hipMemsetAsync(fill, 0, (size_t)NN * 4, stream);
  hipMemsetAsync(wdeg, 0, (size_t)NN * 4, stream);
  hipMemsetAsync(h0,   0, (size_t)NN * BD * 4, stream);

  hist_kernel   <<<(EE + 255) / 256, 256, 0, stream>>>(node_out, ew, cnti, wdeg);
  scan_kernel   <<<1, 1024, 0, stream>>>(cnti, rowp, wdeg, stats, cntf);
  scales_kernel <<<(NN + 255) / 256, 256, 0, stream>>>(wdeg, stats, scales);
  scatter_kernel<<<(EE + 255) / 256, 256, 0, stream>>>(node_in, node_out, relation, ew,
                                                       rowp, fill, snin, srel, sw);
  init_kernel   <<<1, 128, 0, stream>>>(h_index, r_index, qemb, query, h0);

  float* hin = h0; float* hout = h1;
  for (int l = 0; l < LL; ++l) {
    relin_kernel<<<(R2C * BD + 255) / 256, 256, 0, stream>>>(
        query, relW + (size_t)l * DD * R2C * DD, relB + (size_t)l * R2C * DD, relIn);
    layer_kernel<<<(NN + NPB - 1) / NPB, 128, 0, stream>>>(
        hin, hout, relIn, snin, srel, sw, rowp, cntf, scales,
        linW + (size_t)l * THD * DD, linB + (size_t)l * DD, h_index, query);
    float* tmp = hin; hin = hout; hout = tmp;
  }
  mlp_kernel<<<(NN + NPB - 1) / NPB, 128, 0, stream>>>(hin, query, W1, b1, W2, b2, out);
}

// Round 2
// 990.661 us; speedup vs baseline: 1.1319x; 1.1319x over previous
//
#include <hip/hip_runtime.h>

#define NN  25000
#define EE  500000
#define BB  4
#define DD  32
#define R2C 474
#define LL  4
#define BD  128      // B*D
#define THD 416      // 13*D
#define EPSF 1e-6f
#define NPB 2        // nodes per block: 12500 blocks -> saturate 16-block/CU cap

// ---------------- CSR build ----------------
__global__ __launch_bounds__(256) void hist_kernel(const int* __restrict__ node_out,
                                                   const float* __restrict__ ew,
                                                   int* __restrict__ cnt,
                                                   float* __restrict__ wdeg) {
  int e = blockIdx.x * 256 + threadIdx.x;
  if (e < EE) {
    int d = node_out[e];
    atomicAdd(&cnt[d], 1);
    atomicAdd(&wdeg[d], ew[e]);
  }
}

__global__ __launch_bounds__(1024) void scan_kernel(const int* __restrict__ cnt,
                                                    int* __restrict__ rowp,
                                                    const float* __restrict__ wdeg,
                                                    float* __restrict__ stats,
                                                    float* __restrict__ cntf) {
  __shared__ int   part[1024];
  __shared__ float fpart[1024];
  int t = threadIdx.x;
  const int per = (NN + 1023) / 1024;   // 25
  int beg = t * per, end = min(beg + per, NN);
  int s = 0; float ls = 0.f;
  for (int i = beg; i < end; ++i) { s += cnt[i]; ls += logf(wdeg[i] + 1.0f); }
  part[t] = s; fpart[t] = ls;
  __syncthreads();
  for (int off = 1; off < 1024; off <<= 1) {
    int   v  = (t >= off) ? part[t - off]  : 0;
    float fv = (t >= off) ? fpart[t - off] : 0.f;
    __syncthreads();
    part[t] += v; fpart[t] += fv;
    __syncthreads();
  }
  int run = part[t] - s;   // exclusive prefix of this thread's chunk
  for (int i = beg; i < end; ++i) {
    rowp[i] = run; run += cnt[i];
    cntf[i] = (float)(cnt[i] + 1);      // indeg + self entry
  }
  if (t == 1023) { rowp[NN] = part[1023]; stats[0] = fpart[1023]; }
}

__global__ __launch_bounds__(256) void scales_kernel(const float* __restrict__ wdeg,
                                                     const float* __restrict__ stats,
                                                     float* __restrict__ scales) {
  int n = blockIdx.x * 256 + threadIdx.x;
  if (n >= NN) return;
  float mean = stats[0] / (float)NN;
  float sc = logf(wdeg[n] + 1.0f) / mean;
  scales[n * 3 + 0] = 1.0f;
  scales[n * 3 + 1] = sc;
  scales[n * 3 + 2] = 1.0f / fmaxf(sc, 0.01f);
}

// pack each edge as {node_in, relation, w_bits, 0} so the uniform per-edge
// fetch in layer_kernel is ONE s_load_dwordx4
__global__ __launch_bounds__(256) void scatter_kernel(const int* __restrict__ node_in,
                                                      const int* __restrict__ node_out,
                                                      const int* __restrict__ relation,
                                                      const float* __restrict__ ew,
                                                      const int* __restrict__ rowp,
                                                      int* __restrict__ fill,
                                                      int4* __restrict__ ep) {
  int e = blockIdx.x * 256 + threadIdx.x;
  if (e >= EE) return;
  int dn = node_out[e];
  int pos = rowp[dn] + atomicAdd(&fill[dn], 1);
  ep[pos] = make_int4(node_in[e], relation[e], __float_as_int(ew[e]), 0);
}

// query gather + boundary placement (h0 pre-zeroed by memset)
__global__ __launch_bounds__(128) void init_kernel(const int* __restrict__ h_index,
                                                   const int* __restrict__ r_index,
                                                   const float* __restrict__ qemb,
                                                   float* __restrict__ query,
                                                   float* __restrict__ h0) {
  int t = threadIdx.x; int b = t >> 5, d = t & 31;
  float qv = qemb[r_index[b] * DD + d];
  query[t] = qv;
  h0[h_index[b] * BD + t] = qv;
}

// rel_in[r][b][d] = query[b] . rel_W[l][:, r*D+d] + rel_b[l][r*D+d]
__global__ __launch_bounds__(256) void relin_kernel(const float* __restrict__ query,
                                                    const float* __restrict__ relW,
                                                    const float* __restrict__ relB,
                                                    float* __restrict__ relIn) {
  int o = blockIdx.x * 256 + threadIdx.x;
  if (o >= R2C * BD) return;
  int r = o >> 7; int b = (o >> 5) & 3; int d = o & 31;
  int col = r * DD + d;
  float acc = relB[col];
  #pragma unroll
  for (int k = 0; k < DD; ++k)
    acc = fmaf(query[b * DD + k], relW[(size_t)k * (R2C * DD) + col], acc);
  relIn[o] = acc;   // o == r*128 + b*32 + d
}

// main fused layer: gather-reduce PNA stats + scales + 416->32 linear + relu
// feat13 exchange is within a 32-lane b-group (wave-disjoint) -> NO barriers.
// LDS update layout [si*3+sc][32]: lanes write consecutive addrs -> no conflicts.
__global__ __launch_bounds__(128) void layer_kernel(const float* __restrict__ hin,
                                                    float* __restrict__ hout,
                                                    const float* __restrict__ relIn,
                                                    const int4* __restrict__ ep,
                                                    const int* __restrict__ rowp,
                                                    const float* __restrict__ cntf,
                                                    const float* __restrict__ scales,
                                                    const float* __restrict__ W,
                                                    const float* __restrict__ bias,
                                                    const int* __restrict__ h_index,
                                                    const float* __restrict__ query) {
  __shared__ float feat13[BB][THD];
  const int t = threadIdx.x;
  const int b = t >> 5, d = t & 31;
  const float qv = query[t];
  const int   hb = h_index[b];
  const float bj = bias[d];
  float* fb = &feat13[b][0];
  int n0 = blockIdx.x * NPB;
  int n1 = min(n0 + NPB, NN);
  for (int n = n0; n < n1; ++n) {
    int beg = rowp[n], end = rowp[n + 1];
    // boundary self-message (weight 1) initializes all four accumulators
    float msgb = (n == hb) ? qv : 0.f;
    float s = msgb, q = msgb * msgb, mx = msgb, mn = msgb;
    float hs = hin[(size_t)n * BD + t];
    int p = beg;
    // unroll-4: 8 independent vector gathers in flight per lane
    for (; p + 4 <= end; p += 4) {
      int4 e0 = ep[p];     int4 e1 = ep[p + 1];
      int4 e2 = ep[p + 2]; int4 e3 = ep[p + 3];
      float hv0 = hin[(size_t)e0.x * BD + t];
      float rv0 = relIn[(size_t)e0.y * BD + t];
      float hv1 = hin[(size_t)e1.x * BD + t];
      float rv1 = relIn[(size_t)e1.y * BD + t];
      float hv2 = hin[(size_t)e2.x * BD + t];
      float rv2 = relIn[(size_t)e2.y * BD + t];
      float hv3 = hin[(size_t)e3.x * BD + t];
      float rv3 = relIn[(size_t)e3.y * BD + t];
      float m0 = rv0 * hv0, mw0 = m0 * __int_as_float(e0.z);
      float m1 = rv1 * hv1, mw1 = m1 * __int_as_float(e1.z);
      float m2 = rv2 * hv2, mw2 = m2 * __int_as_float(e2.z);
      float m3 = rv3 * hv3, mw3 = m3 * __int_as_float(e3.z);
      s += mw0; q = fmaf(m0, mw0, q); mx = fmaxf(mx, mw0); mn = fminf(mn, mw0);
      s += mw1; q = fmaf(m1, mw1, q); mx = fmaxf(mx, mw1); mn = fminf(mn, mw1);
      s += mw2; q = fmaf(m2, mw2, q); mx = fmaxf(mx, mw2); mn = fminf(mn, mw2);
      s += mw3; q = fmaf(m3, mw3, q); mx = fmaxf(mx, mw3); mn = fminf(mn, mw3);
    }
    for (; p < end; ++p) {
      int4 e = ep[p];
      float hv = hin[(size_t)e.x * BD + t];
      float rv = relIn[(size_t)e.y * BD + t];
      float m = rv * hv, mw = m * __int_as_float(e.z);
      s += mw; q = fmaf(m, mw, q); mx = fmaxf(mx, mw); mn = fminf(mn, mw);
    }
    float invc = 1.0f / cntf[n];
    float mean = s * invc;
    float sq   = q * invc;
    float sd   = sqrtf(fmaxf(sq - mean * mean, EPSF));
    float sc1 = scales[n * 3 + 1], sc2 = scales[n * 3 + 2];
    float fv[4] = {mean, mx, mn, sd};
    // conflict-free writes: [d] then [(si*3+sc)*32 + d]
    fb[d] = hs;
    #pragma unroll
    for (int si = 0; si < 4; ++si) {
      float v = fv[si];
      fb[DD + (si * 3 + 0) * 32 + d] = v;
      fb[DD + (si * 3 + 1) * 32 + d] = v * sc1;
      fb[DD + (si * 3 + 2) * 32 + d] = v * sc2;
    }
    // linear 416->32: iterate in LDS order, index W by reference order.
    // ref feature index for LDS slot (si,sc,df) = 32 + (df*4+si)*3 + sc
    float acc = bj;
    #pragma unroll 8
    for (int i = 0; i < DD; ++i)
      acc = fmaf(fb[i], W[i * DD + d], acc);
    #pragma unroll
    for (int si = 0; si < 4; ++si) {
      #pragma unroll
      for (int sc = 0; sc < 3; ++sc) {
        const float* fp = fb + DD + (si * 3 + sc) * 32;
        const float* wp = W + (DD + si * 3 + sc) * DD + d;
        #pragma unroll 8
        for (int df = 0; df < 32; ++df)
          acc = fmaf(fp[df], wp[(size_t)df * 12 * DD], acc);
      }
    }
    hout[(size_t)n * BD + t] = fmaxf(acc, 0.f);
    // no barrier: fb region is exclusive to this wave's b-group, wave is lockstep
  }
}

// final MLP: [hidden, query] (64) -> relu(64) -> 1, write out[b*N + n]
__global__ __launch_bounds__(128) void mlp_kernel(const float* __restrict__ hin,
                                                  const float* __restrict__ query,
                                                  const float* __restrict__ W1,
                                                  const float* __restrict__ b1,
                                                  const float* __restrict__ W2,
                                                  const float* __restrict__ b2,
                                                  float* __restrict__ out) {
  __shared__ float f2[BB][2 * DD];
  const int t = threadIdx.x;
  const int b = t >> 5, d = t & 31;
  const float qv = query[t];
  const float w2a = W2[d], w2b = W2[DD + d];
  const float b1a = b1[d], b1b = b1[DD + d];
  const float b2v = b2[0];
  const int NPBM = 8;
  int n0 = blockIdx.x * NPBM, n1 = min(n0 + NPBM, NN);
  for (int n = n0; n < n1; ++n) {
    // f2[b] is wave-private (b-groups wave-disjoint) -> no barriers
    f2[b][d]      = hin[(size_t)n * BD + t];
    f2[b][DD + d] = qv;
    float a0 = b1a, a1 = b1b;
    #pragma unroll
    for (int i = 0; i < 2 * DD; ++i) {
      float v = f2[b][i];
      a0 = fmaf(v, W1[i * 2 * DD + d], a0);
      a1 = fmaf(v, W1[i * 2 * DD + DD + d], a1);
    }
    a0 = fmaxf(a0, 0.f); a1 = fmaxf(a1, 0.f);
    float part = a0 * w2a + a1 * w2b;
    #pragma unroll
    for (int off = 16; off > 0; off >>= 1) part += __shfl_down(part, off, 32);
    if (d == 0) out[b * NN + n] = part + b2v;
  }
}

extern "C" void kernel_launch(void* const* d_in, const int* in_sizes, int n_in,
                              void* d_out, int out_size, void* d_ws, size_t ws_size,
                              hipStream_t stream) {
  const int*   node_in  = (const int*)d_in[0];
  const int*   node_out = (const int*)d_in[1];
  const int*   relation = (const int*)d_in[2];
  const float* ew       = (const float*)d_in[3];
  const int*   h_index  = (const int*)d_in[4];
  const int*   r_index  = (const int*)d_in[5];
  const float* qemb     = (const float*)d_in[6];
  const float* relW     = (const float*)d_in[7];
  const float* relB     = (const float*)d_in[8];
  const float* linW     = (const float*)d_in[9];
  const float* linB     = (const float*)d_in[10];
  const float* W1       = (const float*)d_in[11];
  const float* b1       = (const float*)d_in[12];
  const float* W2       = (const float*)d_in[13];
  const float* b2       = (const float*)d_in[14];
  float* out = (float*)d_out;

  char* ws = (char*)d_ws;
  size_t off = 0;
  auto alloc = [&](size_t bytes) -> char* {
    char* p = ws + off;
    off += (bytes + 255) & ~(size_t)255;
    return p;
  };
  float* h0     = (float*)alloc((size_t)NN * BD * 4);
  float* h1     = (float*)alloc((size_t)NN * BD * 4);
  float* relIn  = (float*)alloc((size_t)R2C * BD * 4);
  int4*  ep     = (int4*) alloc((size_t)EE * 16);
  int*   rowp   = (int*)  alloc((size_t)(NN + 1) * 4);
  int*   cnti   = (int*)  alloc((size_t)NN * 4);
  int*   fill   = (int*)  alloc((size_t)NN * 4);
  float* wdeg   = (float*)alloc((size_t)NN * 4);
  float* cntf   = (float*)alloc((size_t)NN * 4);
  float* scales = (float*)alloc((size_t)NN * 3 * 4);
  float* query  = (float*)alloc((size_t)BD * 4);
  float* stats  = (float*)alloc(256);

  hipMemsetAsync(cnti, 0, (size_t)NN * 4, stream);
  hipMemsetAsync(fill, 0, (size_t)NN * 4, stream);
  hipMemsetAsync(wdeg, 0, (size_t)NN * 4, stream);
  hipMemsetAsync(h0,   0, (size_t)NN * BD * 4, stream);

  hist_kernel   <<<(EE + 255) / 256, 256, 0, stream>>>(node_out, ew, cnti, wdeg);
  scan_kernel   <<<1, 1024, 0, stream>>>(cnti, rowp, wdeg, stats, cntf);
  scales_kernel <<<(NN + 255) / 256, 256, 0, stream>>>(wdeg, stats, scales);
  scatter_kernel<<<(EE + 255) / 256, 256, 0, stream>>>(node_in, node_out, relation, ew,
                                                       rowp, fill, ep);
  init_kernel   <<<1, 128, 0, stream>>>(h_index, r_index, qemb, query, h0);

  float* hin = h0; float* hout = h1;
  for (int l = 0; l < LL; ++l) {
    relin_kernel<<<(R2C * BD + 255) / 256, 256, 0, stream>>>(
        query, relW + (size_t)l * DD * R2C * DD, relB + (size_t)l * R2C * DD, relIn);
    layer_kernel<<<(NN + NPB - 1) / NPB, 128, 0, stream>>>(
        hin, hout, relIn, ep, rowp, cntf, scales,
        linW + (size_t)l * THD * DD, linB + (size_t)l * DD, h_index, query);
    float* tmp = hin; hin = hout; hout = tmp;
  }
  mlp_kernel<<<(NN + 7) / 8, 128, 0, stream>>>(hin, query, W1, b1, W2, b2, out);
}